// Round 6
// baseline (255.846 us; speedup 1.0000x reference)
//
#include <hip/hip_runtime.h>
#include <stdint.h>

// Q4_0 dequant-GEMM: y[t,o] = sum_k x[t,k] * s[o,k/32]*(q[o,k]-8) + bias[o]
// M=16 tokens, K=4096, N=11008. HBM floor ~29 us (180 MB qweight @6.3TB/s).
//
// R7 probe: T_qgemm ~= 50 us; harness-fixed window ~= 205 us.
// R8 (barrier-free counted vmcnt): NULL. R4/R6/R8 all identical => limiter
// is NOT sync structure.
//
// R9 theory: every VMEM instr in R4-R8 had adjacent lanes 16 KB apart
// (lane&15 = 16 different weight rows): 32 half-utilized 64-B granule
// requests per instruction, sibling instr re-requesting the same granules
// -> 2x TCP/L2 transaction count + worst-case TA divergence on ~400K VMEM
// instructions. R9 = contiguous staging: each global_load_lds covers
// 4 rows x 256 B contiguous (16 fully-used granules, requested once),
// with SOURCE-side XOR swizzle (slot ^ 2*rowgroup, within each aligned
// 256-B window -> granule set unchanged) so the MFMA readback is 4-way
// bank-conflicted instead of 16-way (T2/m173 both-sides recipe).
// x + scales hoisted to prologue (A-fragments pre-packed, 32 VGPRs):
// per-chunk VMEM = 4 contiguous stage instrs (was 9 scattered).
// Counted-vmcnt depth-1 pipeline kept from R8. Write-once partials kept.

typedef __attribute__((ext_vector_type(8))) short bf16x8;  // 8 bf16 (4 VGPRs)
typedef __attribute__((ext_vector_type(4))) float f32x4;

#define OUT_F 11008
#define IN_F  4096
#define NB    128      // quant blocks along K
#define KSPLIT 4       // K-slices (one per block)
#define CHUNKS 4       // pipelined chunk-iterations per block
#define NTILES (OUT_F / 16)      // 688 output tiles
#define NBLK (NTILES * KSPLIT)   // 2752 blocks
#define M_TOK 16

__global__ __launch_bounds__(256, 4)
void qgemm_kernel(const float* __restrict__ x,
                  const int* __restrict__ qw,
                  const float* __restrict__ scales,
                  const float* __restrict__ bias,
                  float* __restrict__ out,        // used only if part == nullptr
                  float* __restrict__ part) {     // [NBLK][256] partials
  // Stage: [parity][wave][4 KB]. Per wave per chunk: 2 qblocks x 16 rows.
  // Instruction i lands rows 4i..4i+3, 256 B/row, lane-linear (16 B/lane).
  __shared__ uint4 stage[2][4][256];   // 32 KB
  __shared__ float red[4][256];        // 4 KB

  const int bid  = blockIdx.x;
  const int kq   = bid & (KSPLIT - 1);
  const int ob   = (bid >> 2) << 4;        // 16 output features per tile
  const int tid  = threadIdx.x;
  const int wave = tid >> 6;
  const int lane = tid & 63;
  const int col  = lane & 15;              // readback: output row / token
  const int kr   = lane >> 4;              // readback: k sub-chunk 0..3
  const int rg   = lane >> 4;              // staging: row-in-group 0..3
  // staging source slot, XOR-swizzled within the 256-B row window
  const int slot_g = (lane & 15) ^ (2 * rg);

  const int kb_base = kq * (NB / KSPLIT);  // first of this block's 32 qblocks

  // Contiguous staging: instr i covers rows ob+4i+rg, window byte slot_g*16
  // of the wave's 2-qblock (256 B) window. LDS dest lane-linear (16 B/lane),
  // so LDS[i*1024 + rg*256 + s*16] holds global slot s ^ (2*rg).
  auto STAGE = [&](int parity, int t) {
    const int kb0 = kb_base + t * 8 + wave * 2;
#pragma unroll
    for (int i = 0; i < 4; ++i) {
      const char* src = (const char*)qw
          + (size_t)(ob + 4 * i + rg) * (IN_F * 4)
          + (size_t)kb0 * 128 + slot_g * 16;
      __builtin_amdgcn_global_load_lds(
          (const __attribute__((address_space(1))) void*)src,
          (__attribute__((address_space(3))) void*)(&stage[parity][wave][i * 64]),
          16, 0, 0);
    }
  };

  // ---- Prologue ----
  STAGE(0, 0);   // chunk 0 in flight under the A-pack below

  // Hoist x (L2-hot) + scales for all 8 qblocks; pre-pack A-fragments.
  uint32_t Afrag[8][4];
  float    scl[8];
  {
    const float* xbase = x + col * IN_F + kr * 8;
    const float* sbase = scales + (ob + col) * NB;
#pragma unroll
    for (int t = 0; t < CHUNKS; ++t) {
      float2 s2 = *(const float2*)(sbase + kb_base + t * 8 + wave * 2);
      scl[t * 2]     = s2.x;
      scl[t * 2 + 1] = s2.y;
#pragma unroll
      for (int q = 0; q < 2; ++q) {
        const int j  = t * 2 + q;
        const int kb = kb_base + t * 8 + wave * 2 + q;
        const float* xp = xbase + (size_t)kb * 32;
        f32x4 x0 = *(const f32x4*)xp;
        f32x4 x1 = *(const f32x4*)(xp + 4);
        // pack x -> bf16 (round-half-up) via v_perm
        uint32_t a0 = __float_as_uint(x0.x) + 0x8000u;
        uint32_t a1 = __float_as_uint(x0.y) + 0x8000u;
        uint32_t a2 = __float_as_uint(x0.z) + 0x8000u;
        uint32_t a3 = __float_as_uint(x0.w) + 0x8000u;
        uint32_t a4 = __float_as_uint(x1.x) + 0x8000u;
        uint32_t a5 = __float_as_uint(x1.y) + 0x8000u;
        uint32_t a6 = __float_as_uint(x1.z) + 0x8000u;
        uint32_t a7 = __float_as_uint(x1.w) + 0x8000u;
        Afrag[j][0] = __builtin_amdgcn_perm(a1, a0, 0x07060302u);
        Afrag[j][1] = __builtin_amdgcn_perm(a3, a2, 0x07060302u);
        Afrag[j][2] = __builtin_amdgcn_perm(a5, a4, 0x07060302u);
        Afrag[j][3] = __builtin_amdgcn_perm(a7, a6, 0x07060302u);
      }
    }
  }

  // Readback LDS index (uint4 units): row col lives in instr col>>2,
  // row-group col&3; qblock q slot (q*8 + 2*kr), un-swizzled by ^2*(col&3).
  const int rb_base = (col >> 2) * 64 + (col & 3) * 16;
  const int rb_x    = 2 * (col & 3);

  f32x4 acc = {0.f, 0.f, 0.f, 0.f};

#pragma unroll
  for (int t = 0; t < CHUNKS; ++t) {
    if (t + 1 < CHUNKS)
      STAGE((t + 1) & 1, t + 1);       // next chunk: stays in flight past wait
    __builtin_amdgcn_sched_barrier(0); // pin issue order (vmcnt is in-order)
    if (t + 1 < CHUNKS) {
      asm volatile("s_waitcnt vmcnt(4)" ::: "memory");  // chunk t's 4 done
    } else {
      asm volatile("s_waitcnt vmcnt(0)" ::: "memory");
    }
    __builtin_amdgcn_sched_barrier(0); // rule #18: keep ds_read below the wait
#pragma unroll
    for (int q = 0; q < 2; ++q) {
      const int j = t * 2 + q;
      const int idx0 = rb_base + ((q * 8 + 2 * kr) ^ rb_x);
      uint4 q0 = stage[t & 1][wave][idx0];      // bytes kr*32 .. +16 of qblock
      uint4 q1 = stage[t & 1][wave][idx0 + 1];  // bytes kr*32+16 .. +32
      float sc  = scl[j];
      float m8s = -8.f * sc;
      union { uint32_t u[4]; bf16x8 v; } A, B;
      A.u[0] = Afrag[j][0]; A.u[1] = Afrag[j][1];
      A.u[2] = Afrag[j][2]; A.u[3] = Afrag[j][3];
      // dequant: w = s*q - 8s (exact in fp32), truncate-pack to bf16
      uint32_t w0 = __float_as_uint(fmaf((float)(int)q0.x, sc, m8s));
      uint32_t w1 = __float_as_uint(fmaf((float)(int)q0.y, sc, m8s));
      uint32_t w2 = __float_as_uint(fmaf((float)(int)q0.z, sc, m8s));
      uint32_t w3 = __float_as_uint(fmaf((float)(int)q0.w, sc, m8s));
      uint32_t w4 = __float_as_uint(fmaf((float)(int)q1.x, sc, m8s));
      uint32_t w5 = __float_as_uint(fmaf((float)(int)q1.y, sc, m8s));
      uint32_t w6 = __float_as_uint(fmaf((float)(int)q1.z, sc, m8s));
      uint32_t w7 = __float_as_uint(fmaf((float)(int)q1.w, sc, m8s));
      B.u[0] = __builtin_amdgcn_perm(w1, w0, 0x07060302u);
      B.u[1] = __builtin_amdgcn_perm(w3, w2, 0x07060302u);
      B.u[2] = __builtin_amdgcn_perm(w5, w4, 0x07060302u);
      B.u[3] = __builtin_amdgcn_perm(w7, w6, 0x07060302u);
      acc = __builtin_amdgcn_mfma_f32_16x16x32_bf16(A.v, B.v, acc, 0, 0, 0);
    }
    // no barrier: stage buffers are wave-private; the counted wait is the
    // only synchronization needed in the K-loop.
  }

  // Cross-wave combine. C/D layout: lane holds D[row=kr*4+r][col].
#pragma unroll
  for (int r = 0; r < 4; ++r)
    red[wave][(kr * 4 + r) * 16 + col] = acc[r];
  __syncthreads();   // the one real cross-wave sync

  float v = red[0][tid] + red[1][tid] + red[2][tid] + red[3][tid];
  if (part) {
    // write-once partial: [tile*KSPLIT+kq][tid], fully coalesced
    part[(size_t)bid * 256 + tid] = v;
  } else {
    int t = tid >> 4;
    int o = ob + (tid & 15);
    if (kq == 0) v += bias[o];
    __hip_atomic_fetch_add(out + (size_t)t * OUT_F + o, v, __ATOMIC_RELAXED,
                           __HIP_MEMORY_SCOPE_AGENT);
  }
}

// Reduce 4 K-split partials + bias -> out. 176128 outputs, write-once.
// Partials are 2.8 MB written by the previous dispatch -> L2-resident reads.
__global__ __launch_bounds__(256)
void reduce_kernel(const float* __restrict__ part,
                   const float* __restrict__ bias,
                   float* __restrict__ out) {
  int idx = blockIdx.x * 256 + threadIdx.x;   // grid covers exactly 16*11008
  int t = idx / OUT_F;
  int o = idx - t * OUT_F;
  const float* p = part + (size_t)(o >> 4) * (KSPLIT * 256)
                 + ((t << 4) | (o & 15));
  float acc = bias[o];
#pragma unroll
  for (int kq = 0; kq < KSPLIT; ++kq)
    acc += p[kq * 256];
  out[idx] = acc;
}

// ---------------------------------------------------------------------------
extern "C" void kernel_launch(void* const* d_in, const int* in_sizes, int n_in,
                              void* d_out, int out_size, void* d_ws, size_t ws_size,
                              hipStream_t stream) {
  const float* x      = (const float*)d_in[0];
  const int*   qw     = (const int*)d_in[1];
  const float* scales = (const float*)d_in[2];
  const float* bias   = (const float*)d_in[3];
  float* out = (float*)d_out;

  const size_t need = (size_t)NBLK * 256 * sizeof(float);  // 2.8 MB
  if (d_ws != nullptr && ws_size >= need) {
    // Write-once path: no memset, no atomics, no output RMW.
    float* p = (float*)d_ws;
    qgemm_kernel<<<NBLK, 256, 0, stream>>>(x, qw, scales, bias, nullptr, p);
    reduce_kernel<<<(M_TOK * OUT_F) / 256, 256, 0, stream>>>(p, bias, out);
  } else {
    // Fallback: zero-init + atomic K-split accumulate.
    hipMemsetAsync(out, 0, (size_t)M_TOK * OUT_F * sizeof(float), stream);
    qgemm_kernel<<<NBLK, 256, 0, stream>>>(x, qw, scales, bias, out, nullptr);
  }
}